// Round 3
// baseline (33565.762 us; speedup 1.0000x reference)
//
#include <hip/hip_runtime.h>
#include <math.h>

#define T_STEPS 200
#define BATCH   64
#define VOCAB   256
#define EMB     512
#define HN      1024
#define ON_     1024
#define SDIM    4096   // 4*HN
#define NBLK    256
#define BHN     (BATCH * HN)   // 65536

__device__ __forceinline__ float sigmoidf_(float x) {
    return 1.0f / (1.0f + __expf(-x));
}

// ---------------------------------------------------------------------------
// Grid-wide barrier for a persistent 256-block kernel.
// Monotonic generation counter: pass nbar = number of barriers completed+1.
// Agent-scope atomics + __threadfence handle cross-XCD L2 non-coherence.
// ---------------------------------------------------------------------------
__device__ __forceinline__ void grid_barrier(int* cnt, int* gen, int nbar) {
    __syncthreads();
    if (threadIdx.x == 0) {
        __threadfence();   // release: h-writes visible device-wide
        int v = __hip_atomic_fetch_add(cnt, 1, __ATOMIC_ACQ_REL, __HIP_MEMORY_SCOPE_AGENT);
        if (v == NBLK - 1) {
            __hip_atomic_store(cnt, 0, __ATOMIC_RELAXED, __HIP_MEMORY_SCOPE_AGENT);
            __hip_atomic_fetch_add(gen, 1, __ATOMIC_RELEASE, __HIP_MEMORY_SCOPE_AGENT);
        } else {
            while (__hip_atomic_load(gen, __ATOMIC_ACQUIRE, __HIP_MEMORY_SCOPE_AGENT) < nbar) {
                __builtin_amdgcn_s_sleep(1);
            }
        }
        __threadfence();   // acquire: invalidate stale lines before reading h
    }
    __syncthreads();
}

// ---------------------------------------------------------------------------
// One cell GEMM: acc += concat(A1[64,K1], A2[64,K2]) @ Wblk (16 cols of W).
// K1, K2 multiples of 64. 8 waves K-split partial sums.
// W prefetch 2-deep (L3 latency ~700cy > per-kb compute ~512cy); A 1-deep.
// ---------------------------------------------------------------------------
__device__ __forceinline__ void cell_gemm(
    const float* __restrict__ A1, int K1,
    const float* __restrict__ A2, int K2,
    const float* __restrict__ W, int NKB, int colbase,
    int tid, int wv, int lane, int r0, int cc0,
    float (*As)[66], float (*Ws)[16], float (&acc)[4][4])
{
    float4 pa[2], pw, pw2;
    const int kw = tid >> 2, wg = tid & 3;   // tid<256: W-load identity
    const float* wp = W + (size_t)kw * SDIM + wg * HN + colbase;

    auto issueA = [&](int kb) {
        int kk = kb << 6;
        const float* Ab; int koff, astr;
        if (kk < K1) { Ab = A1; koff = kk;      astr = K1; }
        else         { Ab = A2; koff = kk - K1; astr = K2; }
        #pragma unroll
        for (int q = 0; q < 2; ++q) {
            int e = tid + (q << 9);
            int r = e >> 4, k4 = e & 15;
            pa[q] = *(const float4*)(Ab + (size_t)r * astr + koff + (k4 << 2));
        }
    };

    issueA(0);
    if (tid < 256) {
        pw  = *(const float4*)(wp);
        pw2 = *(const float4*)(wp + (size_t)64 * SDIM);
    }

    for (int kb = 0; kb < NKB; ++kb) {
        __syncthreads();                  // previous tile's consumers done
        #pragma unroll
        for (int q = 0; q < 2; ++q) {
            int e = tid + (q << 9);
            int r = e >> 4, k4 = e & 15;
            As[(k4 << 2) + 0][r] = pa[q].x;
            As[(k4 << 2) + 1][r] = pa[q].y;
            As[(k4 << 2) + 2][r] = pa[q].z;
            As[(k4 << 2) + 3][r] = pa[q].w;
        }
        if (tid < 256) *(float4*)&Ws[kw][wg << 2] = pw;
        __syncthreads();
        // issue next loads before compute: latency hides under FMAs
        if (kb + 1 < NKB) issueA(kb + 1);
        if (tid < 256) {
            pw = pw2;
            if (kb + 2 < NKB)
                pw2 = *(const float4*)(wp + (size_t)(kb + 2) * 64 * SDIM);
        }
        #pragma unroll
        for (int k8 = 0; k8 < 8; ++k8) {
            int k = (wv << 3) + k8;
            float2 a01 = *(const float2*)&As[k][r0];
            float2 a23 = *(const float2*)&As[k][r0 + 2];
            float4 w4  = *(const float4*)&Ws[k][cc0];
            float a[4]  = {a01.x, a01.y, a23.x, a23.y};
            float wr[4] = {w4.x, w4.y, w4.z, w4.w};
            #pragma unroll
            for (int i = 0; i < 4; ++i)
                #pragma unroll
                for (int j = 0; j < 4; ++j)
                    acc[i][j] = fmaf(a[i], wr[j], acc[i][j]);
        }
    }
}

// deterministic 8-wave partial-sum reduce into Sx[16][66]
__device__ __forceinline__ void cell_reduce(
    int tid, int wv, int lane,
    float (*Pred)[64][17], float (*Sx)[66], const float (&acc)[4][4])
{
    #pragma unroll
    for (int i = 0; i < 4; ++i)
        #pragma unroll
        for (int j = 0; j < 4; ++j)
            Pred[wv][lane][(i << 2) + j] = acc[i][j];
    __syncthreads();
    #pragma unroll
    for (int u = 0; u < 2; ++u) {
        int e = (tid << 1) + u;
        int p = e >> 4, ij = e & 15;
        float v = 0.0f;
        #pragma unroll
        for (int w = 0; w < 8; ++w) v += Pred[w][p][ij];   // fixed order
        int i = ij >> 2, j = ij & 3;
        int r  = ((p & 15) << 2) + i;
        int cl = ((p >> 4) << 2) + j;
        Sx[cl][r] = v;
    }
    __syncthreads();
}

// ---------------------------------------------------------------------------
// Persistent 2-layer LSTM: all 200 steps in one launch.
// Block b owns h-columns [4b,4b+4) of both layers; c-states in registers.
// One grid barrier per step (after layer-0 h-write) — see hazard proof in
// journal: B(t+1) ordering covers all h1/h0 WAR/RAW pairs.
// ---------------------------------------------------------------------------
__global__ __launch_bounds__(512, 2)
void lstm_persistent(const float* __restrict__ emb,
                     const float* __restrict__ h0_in,
                     const float* __restrict__ c0_in,
                     const float* __restrict__ h1_in,
                     const float* __restrict__ c1_in,
                     const float* __restrict__ W0, const float* __restrict__ b0v,
                     const float* __restrict__ W1, const float* __restrict__ b1v,
                     float* __restrict__ hb0,   // 2 * BHN ping-pong
                     float* __restrict__ HS,    // T*BHN, h1 outputs
                     int* cnt, int* gen)
{
    __shared__ float As[64][66];
    __shared__ float Ws[64][16];
    __shared__ float Pred[8][64][17];
    __shared__ float Sx[16][66];

    const int tid  = threadIdx.x;
    const int wv   = tid >> 6;
    const int lane = tid & 63;
    const int r0   = (lane & 15) << 2;
    const int cc0  = (lane >> 4) << 2;
    const int colbase = blockIdx.x << 2;

    // gate-thread identity (tid<256): row gr, block-local col gi
    const int gr = tid >> 2;
    const int gi = tid & 3;

    float c0r = 0.0f, c1r = 0.0f;
    float bf0[4], bf1[4];
    if (tid < 256) {
        c0r = c0_in[gr * HN + colbase + gi];
        c1r = c1_in[gr * HN + colbase + gi];
        #pragma unroll
        for (int g = 0; g < 4; ++g) {
            bf0[g] = b0v[g * HN + colbase + gi];
            bf1[g] = b1v[g * HN + colbase + gi];
        }
    }

    int nbar = 0;
    for (int t = 0; t < T_STEPS; ++t) {
        const float* eT  = emb + (size_t)t * BATCH * EMB;
        const float* h0r = (t == 0) ? h0_in : hb0 + (size_t)((t & 1) ^ 1) * BHN;
        float*       h0w = hb0 + (size_t)(t & 1) * BHN;
        const float* h1r = (t == 0) ? h1_in : HS + (size_t)(t - 1) * BHN;
        float*       h1w = HS + (size_t)t * BHN;

        // ---- layer 0 ----
        {
            float acc[4][4] = {};
            cell_gemm(eT, EMB, h0r, HN, W0, (EMB + HN) / 64, colbase,
                      tid, wv, lane, r0, cc0, As, Ws, acc);
            cell_reduce(tid, wv, lane, Pred, Sx, acc);
            if (tid < 256) {
                float fg = sigmoidf_(Sx[gi][gr]      + bf0[0]);
                float ig = sigmoidf_(Sx[4 + gi][gr]  + bf0[1]);
                float og = sigmoidf_(Sx[8 + gi][gr]  + bf0[2]);
                float gg = tanhf(    Sx[12 + gi][gr] + bf0[3]);
                c0r = fg * c0r + ig * gg;
                h0w[gr * HN + colbase + gi] = og * tanhf(c0r);
            }
        }
        ++nbar;
        grid_barrier(cnt, gen, nbar);   // h0(t) visible to all blocks

        // ---- layer 1 ----
        {
            float acc[4][4] = {};
            cell_gemm(h0w, HN, h1r, HN, W1, (HN + HN) / 64, colbase,
                      tid, wv, lane, r0, cc0, As, Ws, acc);
            cell_reduce(tid, wv, lane, Pred, Sx, acc);
            if (tid < 256) {
                float fg = sigmoidf_(Sx[gi][gr]      + bf1[0]);
                float ig = sigmoidf_(Sx[4 + gi][gr]  + bf1[1]);
                float og = sigmoidf_(Sx[8 + gi][gr]  + bf1[2]);
                float gg = tanhf(    Sx[12 + gi][gr] + bf1[3]);
                c1r = fg * c1r + ig * gg;
                h1w[gr * HN + colbase + gi] = og * tanhf(c1r);
            }
        }
        // no barrier: B(t+1) + program order covers h1(t) readers (proof in journal)
    }
}

// ---------------------------------------------------------------------------
// Parallel GEMM: C[M,N] = A[M,K] @ B[K,N] (+bias, opt relu). 128x64 tile.
// ---------------------------------------------------------------------------
__global__ __launch_bounds__(256)
void gemm128(const float* __restrict__ A, const float* __restrict__ B,
             const float* __restrict__ bias, float* __restrict__ C,
             int M, int N, int K, int relu)
{
    __shared__ float As[16][132];
    __shared__ float Bs[16][64];

    const int tid = threadIdx.x;
    const int tx = tid & 15, ty = tid >> 4;
    const int m0 = blockIdx.y << 7, n0 = blockIdx.x << 6;
    float acc[8][4] = {};

    for (int kk = 0; kk < K; kk += 16) {
        #pragma unroll
        for (int i = 0; i < 8; ++i) {
            int e = tid + (i << 8);
            int r = e >> 4, k = e & 15;
            As[k][r] = A[(size_t)(m0 + r) * K + kk + k];
        }
        #pragma unroll
        for (int i = 0; i < 4; ++i) {
            int e = tid + (i << 8);
            int r = e >> 6, c = e & 63;
            Bs[r][c] = B[(size_t)(kk + r) * N + n0 + c];
        }
        __syncthreads();
        #pragma unroll
        for (int k = 0; k < 16; ++k) {
            float4 a0 = *(const float4*)&As[k][(ty << 3)];
            float4 a1 = *(const float4*)&As[k][(ty << 3) + 4];
            float4 b4 = *(const float4*)&Bs[k][(tx << 2)];
            float a[8] = {a0.x, a0.y, a0.z, a0.w, a1.x, a1.y, a1.z, a1.w};
            float b[4] = {b4.x, b4.y, b4.z, b4.w};
            #pragma unroll
            for (int i = 0; i < 8; ++i)
                #pragma unroll
                for (int j = 0; j < 4; ++j)
                    acc[i][j] = fmaf(a[i], b[j], acc[i][j]);
        }
        __syncthreads();
    }

    #pragma unroll
    for (int i = 0; i < 8; ++i) {
        int gm = m0 + (ty << 3) + i;
        float4 o;
        float* op = (float*)&o;
        #pragma unroll
        for (int j = 0; j < 4; ++j) {
            int gn = n0 + (tx << 2) + j;
            float v = acc[i][j] + (bias ? bias[gn] : 0.0f);
            if (relu) v = fmaxf(v, 0.0f);
            op[j] = v;
        }
        *(float4*)&C[(size_t)gm * N + n0 + (tx << 2)] = o;
    }
}

__global__ void init_bar(int* bar) {
    if (threadIdx.x < 32) bar[threadIdx.x] = 0;
}

extern "C" void kernel_launch(void* const* d_in, const int* in_sizes, int n_in,
                              void* d_out, int out_size, void* d_ws, size_t ws_size,
                              hipStream_t stream) {
    const float* inputs     = (const float*)d_in[0];   // (T,B,V)
    const float* h0_in      = (const float*)d_in[1];
    const float* c0_in      = (const float*)d_in[2];
    const float* h1_in      = (const float*)d_in[3];
    const float* c1_in      = (const float*)d_in[4];
    const float* emb_matrix = (const float*)d_in[5];   // (V,E)
    const float* lstm_w0    = (const float*)d_in[6];   // (E+HN, 4HN)
    const float* lstm_b0    = (const float*)d_in[7];
    const float* lstm_w1    = (const float*)d_in[8];   // (2HN, 4HN)
    const float* lstm_b1    = (const float*)d_in[9];
    const float* out_w0     = (const float*)d_in[10];  // (HN, ON)
    const float* out_b0     = (const float*)d_in[11];
    const float* out_w1     = (const float*)d_in[12];  // (ON, V)
    const float* out_b1     = (const float*)d_in[13];
    float* logits = (float*)d_out;                     // (T*B, V)

    const int MB = T_STEPS * BATCH;  // 12800

    // workspace (floats): ~132 MB
    float* ws  = (float*)d_ws;
    float* emb = ws;                               // MB*EMB
    float* hb0 = emb + (size_t)MB * EMB;           // 2*BHN ping-pong
    float* HS  = hb0 + 2 * (size_t)BHN;            // MB*HN (h1 outputs)
    float* hid = HS  + (size_t)MB * HN;            // MB*ON
    int*   bar = (int*)(hid + (size_t)MB * ON_);   // gen=bar[0], cnt=bar[16]

    init_bar<<<dim3(1), 64, 0, stream>>>(bar);

    // emb = inputs @ emb_matrix   (12800 x 256) @ (256 x 512)
    gemm128<<<dim3(EMB / 64, MB / 128), 256, 0, stream>>>(
        inputs, emb_matrix, nullptr, emb, MB, EMB, VOCAB, 0);

    // all 200 steps, one launch
    lstm_persistent<<<dim3(NBLK), 512, 0, stream>>>(
        emb, h0_in, c0_in, h1_in, c1_in,
        lstm_w0, lstm_b0, lstm_w1, lstm_b1,
        hb0, HS, &bar[16], &bar[0]);

    // hid = relu(HS @ out_w0 + out_b0)   (12800 x 1024) @ (1024 x 1024)
    gemm128<<<dim3(ON_ / 64, MB / 128), 256, 0, stream>>>(
        HS, out_w0, out_b0, hid, MB, ON_, HN, 1);

    // logits = hid @ out_w1 + out_b1     (12800 x 1024) @ (1024 x 256)
    gemm128<<<dim3(VOCAB / 64, MB / 128), 256, 0, stream>>>(
        hid, out_w1, out_b1, logits, MB, VOCAB, ON_, 0);
}

// Round 4
// 26635.239 us; speedup vs baseline: 1.2602x; 1.2602x over previous
//
#include <hip/hip_runtime.h>
#include <math.h>

#define T_STEPS 200
#define BATCH   64
#define VOCAB   256
#define EMB     512
#define HN      1024
#define ON_     1024
#define SDIM    4096   // 4*HN
#define NBLK    256
#define BHN     (BATCH * HN)   // 65536

__device__ __forceinline__ float sigmoidf_(float x) {
    return 1.0f / (1.0f + __expf(-x));
}

// LDS: gemm phase and reduce phase never overlap (syncs guard both edges)
struct GemmSmem { float As[128][66]; float Ws[128][16]; };   // 41,984 B
struct RedSmem  { float Pred[8][64][17]; float Sx[16][66]; };// 39,040 B
union CellSmem  { GemmSmem g; RedSmem r; };

// ---------------------------------------------------------------------------
// Grid-wide barrier (persistent 256-block kernel), monotonic generation.
// threadfence release = L2 writeback; acquire = invalidate stale h lines.
// ---------------------------------------------------------------------------
__device__ __forceinline__ void grid_barrier(int* cnt, int* gen, int nbar) {
    __syncthreads();
    if (threadIdx.x == 0) {
        __threadfence();
        int v = __hip_atomic_fetch_add(cnt, 1, __ATOMIC_ACQ_REL, __HIP_MEMORY_SCOPE_AGENT);
        if (v == NBLK - 1) {
            __hip_atomic_store(cnt, 0, __ATOMIC_RELAXED, __HIP_MEMORY_SCOPE_AGENT);
            __hip_atomic_fetch_add(gen, 1, __ATOMIC_RELEASE, __HIP_MEMORY_SCOPE_AGENT);
        } else {
            while (__hip_atomic_load(gen, __ATOMIC_ACQUIRE, __HIP_MEMORY_SCOPE_AGENT) < nbar) {
                __builtin_amdgcn_s_sleep(1);
            }
        }
        __threadfence();
    }
    __syncthreads();
}

// ---------------------------------------------------------------------------
// Cell GEMM: acc += concat(A1[64,K1], A2[64,K2]) @ W[:,16 cols at colbase].
// BK=128, K1/K2 multiples of 128. 8-wave K-split.
// 2-deep register double-buffer prefetch on A (4 float4/thr) and W (1 float4/thr).
// ---------------------------------------------------------------------------
__device__ __forceinline__ void cell_gemm(
    const float* __restrict__ A1, int K1,
    const float* __restrict__ A2, int K2,
    const float* __restrict__ W, int NKB, int colbase,
    int tid, int wv, int r0, int cc0,
    GemmSmem& g, float (&acc)[4][4])
{
    const int f4 = tid & 31;   // k-chunk (float4) index within BK
    const int rb = tid >> 5;   // row base 0..15 (rows rb, rb+16, rb+32, rb+48)
    const int kw = tid >> 2;   // W k-row 0..127
    const int wg = tid & 3;    // gate segment
    const float* wp = W + (size_t)kw * SDIM + wg * HN + colbase;

    float4 paA[4], paB[4], pwA, pwB;

    auto issueA = [&](int kb, float4 (&pa)[4]) {
        const int kk = kb << 7;
        const float* Ab; int koff, astr;
        if (kk < K1) { Ab = A1; koff = kk;      astr = K1; }
        else         { Ab = A2; koff = kk - K1; astr = K2; }
        const float* base = Ab + koff + (f4 << 2);
        #pragma unroll
        for (int q = 0; q < 4; ++q)
            pa[q] = *(const float4*)(base + (size_t)(rb + (q << 4)) * astr);
    };
    auto issueW = [&](int kb, float4& pw) {
        pw = *(const float4*)(wp + ((size_t)(kb << 7)) * SDIM);
    };
    auto commit = [&](const float4 (&pa)[4], const float4& pw) {
        #pragma unroll
        for (int q = 0; q < 4; ++q) {
            const int r = rb + (q << 4);
            g.As[(f4 << 2) + 0][r] = pa[q].x;
            g.As[(f4 << 2) + 1][r] = pa[q].y;
            g.As[(f4 << 2) + 2][r] = pa[q].z;
            g.As[(f4 << 2) + 3][r] = pa[q].w;
        }
        *(float4*)&g.Ws[kw][wg << 2] = pw;
    };
    auto compute = [&]() {
        #pragma unroll
        for (int k8 = 0; k8 < 16; ++k8) {
            int k = (wv << 4) + k8;
            float2 a01 = *(const float2*)&g.As[k][r0];
            float2 a23 = *(const float2*)&g.As[k][r0 + 2];
            float4 w4  = *(const float4*)&g.Ws[k][cc0];
            float a[4]  = {a01.x, a01.y, a23.x, a23.y};
            float wr[4] = {w4.x, w4.y, w4.z, w4.w};
            #pragma unroll
            for (int i = 0; i < 4; ++i)
                #pragma unroll
                for (int j = 0; j < 4; ++j)
                    acc[i][j] = fmaf(a[i], wr[j], acc[i][j]);
        }
    };

    issueA(0, paA); issueW(0, pwA);
    issueA(1, paB); issueW(1, pwB);

    for (int kb = 0; kb < NKB; kb += 2) {       // NKB even (12 or 16)
        __syncthreads();                        // LDS free (prev readers done)
        commit(paA, pwA);
        __syncthreads();                        // tile kb visible
        if (kb + 2 < NKB) { issueA(kb + 2, paA); issueW(kb + 2, pwA); }
        compute();
        __syncthreads();
        commit(paB, pwB);
        __syncthreads();
        if (kb + 3 < NKB) { issueA(kb + 3, paB); issueW(kb + 3, pwB); }
        compute();
    }
    __syncthreads();   // protect union reuse (Pred aliases As)
}

// deterministic 8-wave partial reduce into Sx
__device__ __forceinline__ void cell_reduce(
    int tid, int wv, int lane, RedSmem& r, const float (&acc)[4][4])
{
    #pragma unroll
    for (int i = 0; i < 4; ++i)
        #pragma unroll
        for (int j = 0; j < 4; ++j)
            r.Pred[wv][lane][(i << 2) + j] = acc[i][j];
    __syncthreads();
    #pragma unroll
    for (int u = 0; u < 2; ++u) {
        int e = (tid << 1) + u;
        int p = e >> 4, ij = e & 15;
        float v = 0.0f;
        #pragma unroll
        for (int w = 0; w < 8; ++w) v += r.Pred[w][p][ij];   // fixed order
        int i = ij >> 2, j = ij & 3;
        int rr = ((p & 15) << 2) + i;
        int cl = ((p >> 4) << 2) + j;
        r.Sx[cl][rr] = v;
    }
    __syncthreads();
}

// ---------------------------------------------------------------------------
// Persistent 2-layer LSTM, one barrier per step.
// XCD-aware columns: blocks on one XCD own 128 consecutive h-cols -> weight
// cache lines are fetched once per XCD (kills the 4x over-fetch seen in R3).
// ---------------------------------------------------------------------------
__global__ __launch_bounds__(512, 2)
void lstm_persistent(const float* __restrict__ emb,
                     const float* __restrict__ h0_in,
                     const float* __restrict__ c0_in,
                     const float* __restrict__ h1_in,
                     const float* __restrict__ c1_in,
                     const float* __restrict__ W0, const float* __restrict__ b0v,
                     const float* __restrict__ W1, const float* __restrict__ b1v,
                     float* __restrict__ hb0,
                     float* __restrict__ HS,
                     int* cnt, int* gen)
{
    __shared__ CellSmem sh;

    const int tid  = threadIdx.x;
    const int wv   = tid >> 6;
    const int lane = tid & 63;
    const int r0   = (lane & 15) << 2;
    const int cc0  = (lane >> 4) << 2;

    const int xcd  = blockIdx.x & 7;
    const int slot = blockIdx.x >> 3;
    const int colbase = (xcd << 7) + (slot << 2);   // XCD owns 128 consecutive cols

    const int gr = tid >> 2;   // gate-phase row
    const int gi = tid & 3;    // gate-phase local col

    float c0r = 0.0f, c1r = 0.0f;
    float bf0[4], bf1[4];
    if (tid < 256) {
        c0r = c0_in[gr * HN + colbase + gi];
        c1r = c1_in[gr * HN + colbase + gi];
        #pragma unroll
        for (int gk = 0; gk < 4; ++gk) {
            bf0[gk] = b0v[gk * HN + colbase + gi];
            bf1[gk] = b1v[gk * HN + colbase + gi];
        }
    }

    int nbar = 0;
    for (int t = 0; t < T_STEPS; ++t) {
        const float* eT  = emb + (size_t)t * BATCH * EMB;
        const float* h0r = (t == 0) ? h0_in : hb0 + (size_t)((t & 1) ^ 1) * BHN;
        float*       h0w = hb0 + (size_t)(t & 1) * BHN;
        const float* h1r = (t == 0) ? h1_in : HS + (size_t)(t - 1) * BHN;
        float*       h1w = HS + (size_t)t * BHN;

        // ---- layer 0 ----
        {
            float acc[4][4] = {};
            cell_gemm(eT, EMB, h0r, HN, W0, (EMB + HN) / 128, colbase,
                      tid, wv, r0, cc0, sh.g, acc);
            cell_reduce(tid, wv, lane, sh.r, acc);
            if (tid < 256) {
                float fg = sigmoidf_(sh.r.Sx[gi][gr]      + bf0[0]);
                float ig = sigmoidf_(sh.r.Sx[4 + gi][gr]  + bf0[1]);
                float og = sigmoidf_(sh.r.Sx[8 + gi][gr]  + bf0[2]);
                float gg = tanhf(    sh.r.Sx[12 + gi][gr] + bf0[3]);
                c0r = fg * c0r + ig * gg;
                h0w[gr * HN + colbase + gi] = og * tanhf(c0r);
            }
        }
        ++nbar;
        grid_barrier(cnt, gen, nbar);   // h0(t) visible to all blocks

        // ---- layer 1 ----
        {
            float acc[4][4] = {};
            cell_gemm(h0w, HN, h1r, HN, W1, (HN + HN) / 128, colbase,
                      tid, wv, r0, cc0, sh.g, acc);
            cell_reduce(tid, wv, lane, sh.r, acc);
            if (tid < 256) {
                float fg = sigmoidf_(sh.r.Sx[gi][gr]      + bf1[0]);
                float ig = sigmoidf_(sh.r.Sx[4 + gi][gr]  + bf1[1]);
                float og = sigmoidf_(sh.r.Sx[8 + gi][gr]  + bf1[2]);
                float gg = tanhf(    sh.r.Sx[12 + gi][gr] + bf1[3]);
                c1r = fg * c1r + ig * gg;
                h1w[gr * HN + colbase + gi] = og * tanhf(c1r);
            }
        }
        // B(t+1) + program order covers all h1/h0 hazards (journal proof)
    }
}

// ---------------------------------------------------------------------------
// Parallel GEMM: C[M,N] = A[M,K] @ B[K,N] (+bias, opt relu). 128x64 tile.
// ---------------------------------------------------------------------------
__global__ __launch_bounds__(256)
void gemm128(const float* __restrict__ A, const float* __restrict__ B,
             const float* __restrict__ bias, float* __restrict__ C,
             int M, int N, int K, int relu)
{
    __shared__ float As[16][132];
    __shared__ float Bs[16][64];

    const int tid = threadIdx.x;
    const int tx = tid & 15, ty = tid >> 4;
    const int m0 = blockIdx.y << 7, n0 = blockIdx.x << 6;
    float acc[8][4] = {};

    for (int kk = 0; kk < K; kk += 16) {
        #pragma unroll
        for (int i = 0; i < 8; ++i) {
            int e = tid + (i << 8);
            int r = e >> 4, k = e & 15;
            As[k][r] = A[(size_t)(m0 + r) * K + kk + k];
        }
        #pragma unroll
        for (int i = 0; i < 4; ++i) {
            int e = tid + (i << 8);
            int r = e >> 6, c = e & 63;
            Bs[r][c] = B[(size_t)(kk + r) * N + n0 + c];
        }
        __syncthreads();
        #pragma unroll
        for (int k = 0; k < 16; ++k) {
            float4 a0 = *(const float4*)&As[k][(ty << 3)];
            float4 a1 = *(const float4*)&As[k][(ty << 3) + 4];
            float4 b4 = *(const float4*)&Bs[k][(tx << 2)];
            float a[8] = {a0.x, a0.y, a0.z, a0.w, a1.x, a1.y, a1.z, a1.w};
            float b[4] = {b4.x, b4.y, b4.z, b4.w};
            #pragma unroll
            for (int i = 0; i < 8; ++i)
                #pragma unroll
                for (int j = 0; j < 4; ++j)
                    acc[i][j] = fmaf(a[i], b[j], acc[i][j]);
        }
        __syncthreads();
    }

    #pragma unroll
    for (int i = 0; i < 8; ++i) {
        int gm = m0 + (ty << 3) + i;
        float4 o;
        float* op = (float*)&o;
        #pragma unroll
        for (int j = 0; j < 4; ++j) {
            int gn = n0 + (tx << 2) + j;
            float v = acc[i][j] + (bias ? bias[gn] : 0.0f);
            if (relu) v = fmaxf(v, 0.0f);
            op[j] = v;
        }
        *(float4*)&C[(size_t)gm * N + n0 + (tx << 2)] = o;
    }
}

__global__ void init_bar(int* bar) {
    if (threadIdx.x < 32) bar[threadIdx.x] = 0;
}

extern "C" void kernel_launch(void* const* d_in, const int* in_sizes, int n_in,
                              void* d_out, int out_size, void* d_ws, size_t ws_size,
                              hipStream_t stream) {
    const float* inputs     = (const float*)d_in[0];
    const float* h0_in      = (const float*)d_in[1];
    const float* c0_in      = (const float*)d_in[2];
    const float* h1_in      = (const float*)d_in[3];
    const float* c1_in      = (const float*)d_in[4];
    const float* emb_matrix = (const float*)d_in[5];
    const float* lstm_w0    = (const float*)d_in[6];
    const float* lstm_b0    = (const float*)d_in[7];
    const float* lstm_w1    = (const float*)d_in[8];
    const float* lstm_b1    = (const float*)d_in[9];
    const float* out_w0     = (const float*)d_in[10];
    const float* out_b0     = (const float*)d_in[11];
    const float* out_w1     = (const float*)d_in[12];
    const float* out_b1     = (const float*)d_in[13];
    float* logits = (float*)d_out;

    const int MB = T_STEPS * BATCH;  // 12800

    float* ws  = (float*)d_ws;
    float* emb = ws;                               // MB*EMB
    float* hb0 = emb + (size_t)MB * EMB;           // 2*BHN ping-pong
    float* HS  = hb0 + 2 * (size_t)BHN;            // MB*HN
    float* hid = HS  + (size_t)MB * HN;            // MB*ON
    int*   bar = (int*)(hid + (size_t)MB * ON_);   // gen=bar[0], cnt=bar[16]

    init_bar<<<dim3(1), 64, 0, stream>>>(bar);

    gemm128<<<dim3(EMB / 64, MB / 128), 256, 0, stream>>>(
        inputs, emb_matrix, nullptr, emb, MB, EMB, VOCAB, 0);

    lstm_persistent<<<dim3(NBLK), 512, 0, stream>>>(
        emb, h0_in, c0_in, h1_in, c1_in,
        lstm_w0, lstm_b0, lstm_w1, lstm_b1,
        hb0, HS, &bar[16], &bar[0]);

    gemm128<<<dim3(ON_ / 64, MB / 128), 256, 0, stream>>>(
        HS, out_w0, out_b0, hid, MB, ON_, HN, 1);

    gemm128<<<dim3(VOCAB / 64, MB / 128), 256, 0, stream>>>(
        hid, out_w1, out_b1, logits, MB, VOCAB, ON_, 0);
}

// Round 5
// 26629.153 us; speedup vs baseline: 1.2605x; 1.0002x over previous
//
#include <hip/hip_runtime.h>
#include <math.h>

#define T_STEPS 200
#define BATCH   64
#define VOCAB   256
#define EMB     512
#define HN      1024
#define ON_     1024
#define SDIM    4096   // 4*HN
#define NBLK    256
#define BHN     (BATCH * HN)   // 65536

__device__ __forceinline__ float sigmoidf_(float x) {
    return 1.0f / (1.0f + __expf(-x));
}

// LDS: gemm phase and reduce phase never overlap (syncs guard both edges)
struct GemmSmem { float As[128][66]; float Ws[128][16]; };   // 41,984 B
struct RedSmem  { float Pred[8][64][17]; float Sx[16][66]; };// 39,040 B
union CellSmem  { GemmSmem g; RedSmem r; };

// ---------------------------------------------------------------------------
// Grid-wide barrier (persistent 256-block kernel), monotonic generation.
// threadfence release = L2 writeback; acquire = invalidate stale h lines.
// ---------------------------------------------------------------------------
__device__ __forceinline__ void grid_barrier(int* cnt, int* gen, int nbar) {
    __syncthreads();
    if (threadIdx.x == 0) {
        __threadfence();
        int v = __hip_atomic_fetch_add(cnt, 1, __ATOMIC_ACQ_REL, __HIP_MEMORY_SCOPE_AGENT);
        if (v == NBLK - 1) {
            __hip_atomic_store(cnt, 0, __ATOMIC_RELAXED, __HIP_MEMORY_SCOPE_AGENT);
            __hip_atomic_fetch_add(gen, 1, __ATOMIC_RELEASE, __HIP_MEMORY_SCOPE_AGENT);
        } else {
            while (__hip_atomic_load(gen, __ATOMIC_ACQUIRE, __HIP_MEMORY_SCOPE_AGENT) < nbar) {
                __builtin_amdgcn_s_sleep(1);
            }
        }
        __threadfence();
    }
    __syncthreads();
}

// ---------------------------------------------------------------------------
// Cell GEMM: acc += concat(A1[64,K1], A2[64,K2]) @ W[:,16 cols at colbase].
// BK=128, K1/K2 multiples of 128. 8-wave K-split.
// 2-deep register double-buffer prefetch on A (4 float4/thr) and W (1 float4/thr).
// ---------------------------------------------------------------------------
__device__ __forceinline__ void cell_gemm(
    const float* __restrict__ A1, int K1,
    const float* __restrict__ A2, int K2,
    const float* __restrict__ W, int NKB, int colbase,
    int tid, int wv, int r0, int cc0,
    GemmSmem& g, float (&acc)[4][4])
{
    const int f4 = tid & 31;   // k-chunk (float4) index within BK
    const int rb = tid >> 5;   // row base 0..15 (rows rb, rb+16, rb+32, rb+48)
    const int kw = tid >> 2;   // W k-row 0..127
    const int wg = tid & 3;    // gate segment
    const float* wp = W + (size_t)kw * SDIM + wg * HN + colbase;

    float4 paA[4], paB[4], pwA, pwB;

    auto issueA = [&](int kb, float4 (&pa)[4]) {
        const int kk = kb << 7;
        const float* Ab; int koff, astr;
        if (kk < K1) { Ab = A1; koff = kk;      astr = K1; }
        else         { Ab = A2; koff = kk - K1; astr = K2; }
        const float* base = Ab + koff + (f4 << 2);
        #pragma unroll
        for (int q = 0; q < 4; ++q)
            pa[q] = *(const float4*)(base + (size_t)(rb + (q << 4)) * astr);
    };
    auto issueW = [&](int kb, float4& pw) {
        pw = *(const float4*)(wp + ((size_t)(kb << 7)) * SDIM);
    };
    auto commit = [&](const float4 (&pa)[4], const float4& pw) {
        #pragma unroll
        for (int q = 0; q < 4; ++q) {
            const int r = rb + (q << 4);
            g.As[(f4 << 2) + 0][r] = pa[q].x;
            g.As[(f4 << 2) + 1][r] = pa[q].y;
            g.As[(f4 << 2) + 2][r] = pa[q].z;
            g.As[(f4 << 2) + 3][r] = pa[q].w;
        }
        *(float4*)&g.Ws[kw][wg << 2] = pw;
    };
    auto compute = [&]() {
        #pragma unroll
        for (int k8 = 0; k8 < 16; ++k8) {
            int k = (wv << 4) + k8;
            float2 a01 = *(const float2*)&g.As[k][r0];
            float2 a23 = *(const float2*)&g.As[k][r0 + 2];
            float4 w4  = *(const float4*)&g.Ws[k][cc0];
            float a[4]  = {a01.x, a01.y, a23.x, a23.y};
            float wr[4] = {w4.x, w4.y, w4.z, w4.w};
            #pragma unroll
            for (int i = 0; i < 4; ++i)
                #pragma unroll
                for (int j = 0; j < 4; ++j)
                    acc[i][j] = fmaf(a[i], wr[j], acc[i][j]);
        }
    };

    issueA(0, paA); issueW(0, pwA);
    issueA(1, paB); issueW(1, pwB);

    for (int kb = 0; kb < NKB; kb += 2) {       // NKB even (12 or 16)
        __syncthreads();                        // LDS free (prev readers done)
        commit(paA, pwA);
        __syncthreads();                        // tile kb visible
        if (kb + 2 < NKB) { issueA(kb + 2, paA); issueW(kb + 2, pwA); }
        compute();
        __syncthreads();
        commit(paB, pwB);
        __syncthreads();
        if (kb + 3 < NKB) { issueA(kb + 3, paB); issueW(kb + 3, pwB); }
        compute();
    }
    __syncthreads();   // protect union reuse (Pred aliases As)
}

// deterministic 8-wave partial reduce into Sx
__device__ __forceinline__ void cell_reduce(
    int tid, int wv, int lane, RedSmem& r, const float (&acc)[4][4])
{
    #pragma unroll
    for (int i = 0; i < 4; ++i)
        #pragma unroll
        for (int j = 0; j < 4; ++j)
            r.Pred[wv][lane][(i << 2) + j] = acc[i][j];
    __syncthreads();
    #pragma unroll
    for (int u = 0; u < 2; ++u) {
        int e = (tid << 1) + u;
        int p = e >> 4, ij = e & 15;
        float v = 0.0f;
        #pragma unroll
        for (int w = 0; w < 8; ++w) v += r.Pred[w][p][ij];   // fixed order
        int i = ij >> 2, j = ij & 3;
        int rr = ((p & 15) << 2) + i;
        int cl = ((p >> 4) << 2) + j;
        r.Sx[cl][rr] = v;
    }
    __syncthreads();
}

// ---------------------------------------------------------------------------
// Persistent 2-layer LSTM, one barrier per step.
// XCD-aware columns: blocks on one XCD own 128 consecutive h-cols -> weight
// cache lines are fetched once per XCD (kills the 4x over-fetch seen in R3).
// ---------------------------------------------------------------------------
__global__ __launch_bounds__(512, 2)
void lstm_persistent(const float* __restrict__ emb,
                     const float* __restrict__ h0_in,
                     const float* __restrict__ c0_in,
                     const float* __restrict__ h1_in,
                     const float* __restrict__ c1_in,
                     const float* __restrict__ W0, const float* __restrict__ b0v,
                     const float* __restrict__ W1, const float* __restrict__ b1v,
                     float* __restrict__ hb0,
                     float* __restrict__ HS,
                     int* cnt, int* gen)
{
    __shared__ CellSmem sh;

    const int tid  = threadIdx.x;
    const int wv   = tid >> 6;
    const int lane = tid & 63;
    const int r0   = (lane & 15) << 2;
    const int cc0  = (lane >> 4) << 2;

    const int xcd  = blockIdx.x & 7;
    const int slot = blockIdx.x >> 3;
    const int colbase = (xcd << 7) + (slot << 2);   // XCD owns 128 consecutive cols

    const int gr = tid >> 2;   // gate-phase row
    const int gi = tid & 3;    // gate-phase local col

    float c0r = 0.0f, c1r = 0.0f;
    float bf0[4], bf1[4];
    if (tid < 256) {
        c0r = c0_in[gr * HN + colbase + gi];
        c1r = c1_in[gr * HN + colbase + gi];
        #pragma unroll
        for (int gk = 0; gk < 4; ++gk) {
            bf0[gk] = b0v[gk * HN + colbase + gi];
            bf1[gk] = b1v[gk * HN + colbase + gi];
        }
    }

    int nbar = 0;
    for (int t = 0; t < T_STEPS; ++t) {
        const float* eT  = emb + (size_t)t * BATCH * EMB;
        const float* h0r = (t == 0) ? h0_in : hb0 + (size_t)((t & 1) ^ 1) * BHN;
        float*       h0w = hb0 + (size_t)(t & 1) * BHN;
        const float* h1r = (t == 0) ? h1_in : HS + (size_t)(t - 1) * BHN;
        float*       h1w = HS + (size_t)t * BHN;

        // ---- layer 0 ----
        {
            float acc[4][4] = {};
            cell_gemm(eT, EMB, h0r, HN, W0, (EMB + HN) / 128, colbase,
                      tid, wv, r0, cc0, sh.g, acc);
            cell_reduce(tid, wv, lane, sh.r, acc);
            if (tid < 256) {
                float fg = sigmoidf_(sh.r.Sx[gi][gr]      + bf0[0]);
                float ig = sigmoidf_(sh.r.Sx[4 + gi][gr]  + bf0[1]);
                float og = sigmoidf_(sh.r.Sx[8 + gi][gr]  + bf0[2]);
                float gg = tanhf(    sh.r.Sx[12 + gi][gr] + bf0[3]);
                c0r = fg * c0r + ig * gg;
                h0w[gr * HN + colbase + gi] = og * tanhf(c0r);
            }
        }
        ++nbar;
        grid_barrier(cnt, gen, nbar);   // h0(t) visible to all blocks

        // ---- layer 1 ----
        {
            float acc[4][4] = {};
            cell_gemm(h0w, HN, h1r, HN, W1, (HN + HN) / 128, colbase,
                      tid, wv, r0, cc0, sh.g, acc);
            cell_reduce(tid, wv, lane, sh.r, acc);
            if (tid < 256) {
                float fg = sigmoidf_(sh.r.Sx[gi][gr]      + bf1[0]);
                float ig = sigmoidf_(sh.r.Sx[4 + gi][gr]  + bf1[1]);
                float og = sigmoidf_(sh.r.Sx[8 + gi][gr]  + bf1[2]);
                float gg = tanhf(    sh.r.Sx[12 + gi][gr] + bf1[3]);
                c1r = fg * c1r + ig * gg;
                h1w[gr * HN + colbase + gi] = og * tanhf(c1r);
            }
        }
        // B(t+1) + program order covers all h1/h0 hazards (journal proof)
    }
}

// ---------------------------------------------------------------------------
// Parallel GEMM: C[M,N] = A[M,K] @ B[K,N] (+bias, opt relu). 128x64 tile.
// ---------------------------------------------------------------------------
__global__ __launch_bounds__(256)
void gemm128(const float* __restrict__ A, const float* __restrict__ B,
             const float* __restrict__ bias, float* __restrict__ C,
             int M, int N, int K, int relu)
{
    __shared__ float As[16][132];
    __shared__ float Bs[16][64];

    const int tid = threadIdx.x;
    const int tx = tid & 15, ty = tid >> 4;
    const int m0 = blockIdx.y << 7, n0 = blockIdx.x << 6;
    float acc[8][4] = {};

    for (int kk = 0; kk < K; kk += 16) {
        #pragma unroll
        for (int i = 0; i < 8; ++i) {
            int e = tid + (i << 8);
            int r = e >> 4, k = e & 15;
            As[k][r] = A[(size_t)(m0 + r) * K + kk + k];
        }
        #pragma unroll
        for (int i = 0; i < 4; ++i) {
            int e = tid + (i << 8);
            int r = e >> 6, c = e & 63;
            Bs[r][c] = B[(size_t)(kk + r) * N + n0 + c];
        }
        __syncthreads();
        #pragma unroll
        for (int k = 0; k < 16; ++k) {
            float4 a0 = *(const float4*)&As[k][(ty << 3)];
            float4 a1 = *(const float4*)&As[k][(ty << 3) + 4];
            float4 b4 = *(const float4*)&Bs[k][(tx << 2)];
            float a[8] = {a0.x, a0.y, a0.z, a0.w, a1.x, a1.y, a1.z, a1.w};
            float b[4] = {b4.x, b4.y, b4.z, b4.w};
            #pragma unroll
            for (int i = 0; i < 8; ++i)
                #pragma unroll
                for (int j = 0; j < 4; ++j)
                    acc[i][j] = fmaf(a[i], b[j], acc[i][j]);
        }
        __syncthreads();
    }

    #pragma unroll
    for (int i = 0; i < 8; ++i) {
        int gm = m0 + (ty << 3) + i;
        float4 o;
        float* op = (float*)&o;
        #pragma unroll
        for (int j = 0; j < 4; ++j) {
            int gn = n0 + (tx << 2) + j;
            float v = acc[i][j] + (bias ? bias[gn] : 0.0f);
            if (relu) v = fmaxf(v, 0.0f);
            op[j] = v;
        }
        *(float4*)&C[(size_t)gm * N + n0 + (tx << 2)] = o;
    }
}

__global__ void init_bar(int* bar) {
    if (threadIdx.x < 32) bar[threadIdx.x] = 0;
}

extern "C" void kernel_launch(void* const* d_in, const int* in_sizes, int n_in,
                              void* d_out, int out_size, void* d_ws, size_t ws_size,
                              hipStream_t stream) {
    const float* inputs     = (const float*)d_in[0];
    const float* h0_in      = (const float*)d_in[1];
    const float* c0_in      = (const float*)d_in[2];
    const float* h1_in      = (const float*)d_in[3];
    const float* c1_in      = (const float*)d_in[4];
    const float* emb_matrix = (const float*)d_in[5];
    const float* lstm_w0    = (const float*)d_in[6];
    const float* lstm_b0    = (const float*)d_in[7];
    const float* lstm_w1    = (const float*)d_in[8];
    const float* lstm_b1    = (const float*)d_in[9];
    const float* out_w0     = (const float*)d_in[10];
    const float* out_b0     = (const float*)d_in[11];
    const float* out_w1     = (const float*)d_in[12];
    const float* out_b1     = (const float*)d_in[13];
    float* logits = (float*)d_out;

    const int MB = T_STEPS * BATCH;  // 12800

    float* ws  = (float*)d_ws;
    float* emb = ws;                               // MB*EMB
    float* hb0 = emb + (size_t)MB * EMB;           // 2*BHN ping-pong
    float* HS  = hb0 + 2 * (size_t)BHN;            // MB*HN
    float* hid = HS  + (size_t)MB * HN;            // MB*ON
    int*   bar = (int*)(hid + (size_t)MB * ON_);   // gen=bar[0], cnt=bar[16]

    init_bar<<<dim3(1), 64, 0, stream>>>(bar);

    gemm128<<<dim3(EMB / 64, MB / 128), 256, 0, stream>>>(
        inputs, emb_matrix, nullptr, emb, MB, EMB, VOCAB, 0);

    lstm_persistent<<<dim3(NBLK), 512, 0, stream>>>(
        emb, h0_in, c0_in, h1_in, c1_in,
        lstm_w0, lstm_b0, lstm_w1, lstm_b1,
        hb0, HS, &bar[16], &bar[0]);

    gemm128<<<dim3(ON_ / 64, MB / 128), 256, 0, stream>>>(
        HS, out_w0, out_b0, hid, MB, ON_, HN, 1);

    gemm128<<<dim3(VOCAB / 64, MB / 128), 256, 0, stream>>>(
        hid, out_w1, out_b1, logits, MB, VOCAB, ON_, 0);
}